// Round 12
// baseline (76.734 us; speedup 1.0000x reference)
//
#include <hip/hip_runtime.h>
#include <hip/hip_bf16.h>

typedef short short8 __attribute__((ext_vector_type(8)));
typedef float f32x4 __attribute__((ext_vector_type(4)));
typedef unsigned short u16x4 __attribute__((ext_vector_type(4)));

#define D_ 256
#define K_ 1024
#define HW_ 1024
#define NROWS_ 32768
#define QELEMS 8388608  // 32*256*32*32
#define NBLK_ (NROWS_ / 64)

static __device__ __forceinline__ unsigned short to_bf16(float v) {
    __hip_bfloat16 h = __float2bfloat16(v);
    return *(unsigned short*)&h;
}

// ---------------- prep: emb -> bf16 codebook ebf[k][d], enorm[k]=sum e^2, zero counts/loss/done
__global__ __launch_bounds__(256) void vq_prep(const float* __restrict__ emb,
    unsigned short* __restrict__ ebf, float* __restrict__ enorm,
    int* __restrict__ counts, double* __restrict__ loss_acc, int* __restrict__ done)
{
    int k = blockIdx.x, t = threadIdx.x;           // k in [0,1024), t in [0,256)
    float v = emb[k * D_ + t];
    ebf[k * D_ + t] = to_bf16(v);
    float s = v * v;
    for (int o = 32; o > 0; o >>= 1) s += __shfl_down(s, o);
    __shared__ float ws4[4];
    if ((t & 63) == 0) ws4[t >> 6] = s;
    __syncthreads();
    if (t == 0) enorm[k] = ws4[0] + ws4[1] + ws4[2] + ws4[3];
    if (k < 4) counts[k * 256 + t] = 0;
    if (k == 0 && t == 0) { *loss_acc = 0.0; *done = 0; }
}

// ---------------- main: 64 rows/block, 8 waves. Ping-pong codebook staging, MFMA argmin,
// enc-zero writes interleaved into the chunk loop, fused scatter/enc/loss, last block does fin.
__global__ __launch_bounds__(512, 4) void vq_main(
    const float* __restrict__ x, const float* __restrict__ emb,
    const unsigned short* __restrict__ ebf, const float* __restrict__ enorm,
    int* __restrict__ counts, double* __restrict__ loss_acc, int* __restrict__ done,
    float* __restrict__ out)
{
    // union: [xs 32K | es half0 32K..] overlapped later by q_lds [64][65] float4 = 66560 B
    __shared__ char smem[66560];
    __shared__ float xn[64][33];              // per-row |x|^2 partials
    __shared__ float rminv[64][4];
    __shared__ int   rmini[64][4];
    __shared__ int   bestsh[64];
    __shared__ double sred2[8];
    __shared__ int lastflag;

    unsigned short* xs = (unsigned short*)smem;   // [0, 32K) during x-stage
    char* es = smem;                              // chunk halves at +0 / +32768

    const int t = threadIdx.x;
    const int n0 = blockIdx.x * 64;
    const int b = n0 >> 10;
    const int hw0 = n0 & 1023;
    const float* xbase = x + (size_t)b * (D_ * HW_) + hw0;

    // ---- stage x -> bf16 LDS: float4 loads along hw, 4x4 register transpose, b64 writes
    {
        const int rt = t & 15;          // rows 4rt..4rt+3
        const int dg = t >> 4;          // 0..31
        const int r0 = rt * 4;
        float xp[4] = {0.f, 0.f, 0.f, 0.f};
#pragma unroll
        for (int m = 0; m < 2; ++m) {
            int d0 = (dg + 32 * m) * 4;
            f32x4 c[4];
#pragma unroll
            for (int q = 0; q < 4; ++q)
                c[q] = *(const f32x4*)(xbase + (size_t)(d0 + q) * HW_ + r0);
#pragma unroll
            for (int i = 0; i < 4; ++i) {
                u16x4 pk;
                pk[0] = to_bf16(c[0][i]); pk[1] = to_bf16(c[1][i]);
                pk[2] = to_bf16(c[2][i]); pk[3] = to_bf16(c[3][i]);
                xp[i] = fmaf(c[0][i], c[0][i], xp[i]);
                xp[i] = fmaf(c[1][i], c[1][i], xp[i]);
                xp[i] = fmaf(c[2][i], c[2][i], xp[i]);
                xp[i] = fmaf(c[3][i], c[3][i], xp[i]);
                int r = r0 + i;
                int byte = (r * 512 + d0 * 2) ^ ((r & 7) << 4);
                *(u16x4*)((char*)xs + byte) = pk;
            }
        }
#pragma unroll
        for (int i = 0; i < 4; ++i) xn[r0 + i][dg] = xp[i];
    }
    __syncthreads();

    const int lane = t & 63;
    const int w = t >> 6;          // wave 0..7
    const int rh = w & 1;          // row half (32 rows)
    const int cq = w >> 1;         // 16-code tile within 64-chunk
    const int col = lane & 15;
    const int kg = lane >> 4;      // k-group 0..3
    const char* ebf_bytes = (const char*)ebf;
    const int wbyte = w * 4096;

    // ---- prologue: issue stage of chunk 0 -> half1 (doesn't touch xs)
    {
#pragma unroll
        for (int j = 0; j < 4; ++j) {
            int p = wbyte + j * 1024 + lane * 16;
            int qq = p ^ (((p >> 9) & 7) << 4);     // inverse-swizzled source
            __builtin_amdgcn_global_load_lds(ebf_bytes + qq, es + 32768 + wbyte + j * 1024, 16, 0, 0);
        }
    }

    // ---- A fragments: this wave's 32 rows (2 tiles of 16), whole kernel in registers
    short8 areg[2][8];
#pragma unroll
    for (int rt = 0; rt < 2; ++rt) {
        int row = rh * 32 + rt * 16 + col;
        int rowb = row * 512;
        int sw = (row & 7) << 4;
#pragma unroll
        for (int dc = 0; dc < 8; ++dc) {
            int byte = (rowb + dc * 64 + kg * 16) ^ sw;
            areg[rt][dc] = *(const short8*)((const char*)xs + byte);
        }
    }

    float v1[8]; int i1[8];
#pragma unroll
    for (int s = 0; s < 8; ++s) { v1[s] = 3.4e38f; i1[s] = 0x7fffffff; }

    float2* ezw = (float2*)(out + 8388610 + (size_t)(n0 + w * 8) * 1024);
    const float2 zz2 = {0.f, 0.f};

    for (int cc = 0; cc < 16; ++cc) {
        __syncthreads();   // chunk cc resident; all waves done with the half we stage next
        const int hc = ((cc & 1) ^ 1) * 32768;
        if (cc < 15) {     // issue next-chunk stage into other half; overlaps compute below
            const char* src = ebf_bytes + (size_t)(cc + 1) * 32768;
            const int hn = (cc & 1) * 32768;
#pragma unroll
            for (int j = 0; j < 4; ++j) {
                int p = wbyte + j * 1024 + lane * 16;
                int qq = p ^ (((p >> 9) & 7) << 4);
                __builtin_amdgcn_global_load_lds(src + qq, es + hn + wbyte + j * 1024, 16, 0, 0);
            }
        }
        // ---- interleaved encodings zero-stream: 4 x 512B per wave per chunk
        {
            float2* ez = ezw + cc * 256;
#pragma unroll
            for (int j = 0; j < 4; ++j) ez[j * 64 + lane] = zz2;
        }
        const int c0 = cq * 16 + col;
        const int sw0 = (c0 & 7) << 4;
        f32x4 acc0 = {0.f, 0.f, 0.f, 0.f};
        f32x4 acc1 = {0.f, 0.f, 0.f, 0.f};
#pragma unroll
        for (int dc = 0; dc < 8; ++dc) {
            short8 bf = *(const short8*)(es + hc + ((c0 * 512 + dc * 64 + kg * 16) ^ sw0));
            acc0 = __builtin_amdgcn_mfma_f32_16x16x32_bf16(areg[0][dc], bf, acc0, 0, 0, 0);
            acc1 = __builtin_amdgcn_mfma_f32_16x16x32_bf16(areg[1][dc], bf, acc1, 0, 0, 0);
        }
        int code = cc * 64 + c0;
        float bn = enorm[code];   // L1-cached
#pragma unroll
        for (int r = 0; r < 4; ++r) {
            float dv = fmaf(-2.f, acc0[r], bn);
            if (dv < v1[r]) { v1[r] = dv; i1[r] = code; }
            float dw = fmaf(-2.f, acc1[r], bn);
            if (dw < v1[4 + r]) { v1[4 + r] = dw; i1[4 + r] = code; }
        }
    }

    // ---- butterfly min over 16 cols (lane bits 0-3), tie -> lower index
#pragma unroll
    for (int mask = 1; mask < 16; mask <<= 1) {
#pragma unroll
        for (int s = 0; s < 8; ++s) {
            float ov = __shfl_xor(v1[s], mask);
            int oi = __shfl_xor(i1[s], mask);
            if (ov < v1[s] || (ov == v1[s] && oi < i1[s])) { v1[s] = ov; i1[s] = oi; }
        }
    }
    if (col == 0) {
#pragma unroll
        for (int s = 0; s < 8; ++s) {
            int rt = s >> 2, r = s & 3;
            int row = rh * 32 + rt * 16 + kg * 4 + r;
            rminv[row][cq] = v1[s];
            rmini[row][cq] = i1[s];
        }
    }
    __syncthreads();   // also gates: all waves finished reading es before smem reuse

    // ---- finalize (wave 0): pick across 4 code tiles, counts/loss/bestsh
    if (t < 64) {
        float dmin = rminv[t][0]; int best = rmini[t][0];
#pragma unroll
        for (int g = 1; g < 4; ++g) {
            float cv = rminv[t][g]; int ci = rmini[t][g];
            if (cv < dmin || (cv == dmin && ci < best)) { dmin = cv; best = ci; }
        }
        bestsh[t] = best;
        atomicAdd(&counts[best], 1);
        float s = 0.f;
#pragma unroll 8
        for (int g = 0; g < 32; ++g) s += xn[t][g];
        float lrow = dmin + s;     // |x-e|^2 = (|e|^2 - 2x.e) + |x|^2
        for (int o = 32; o > 0; o >>= 1) lrow += __shfl_down(lrow, o);
        if (t == 0) atomicAdd(loss_acc, (double)lrow);
    }
    __syncthreads();

    // ---- gather chosen fp32 codebook rows coalesced into q_lds [64][65] float4
    {
        int r = w * 8 + (lane & 7);          // row within tile
        int c = lane >> 3;                   // 0..7: 32-float segment
        const f32x4* src4 = (const f32x4*)emb + (size_t)bestsh[r] * 64 + c * 8;
        f32x4* dst4 = (f32x4*)smem + r * 65 + c * 8;
#pragma unroll
        for (int j = 0; j < 8; ++j) dst4[j] = src4[j];
    }
    __syncthreads();

    // ---- write quantized out[b][d][hw0+hwr] (wave = 256B contiguous per d)
    {
        const int hwr = t & 63;
        const int dq = t >> 6;               // 0..7
        float* outq = out + 1 + (size_t)b * (D_ * HW_) + hw0 + hwr;
        const float* qrow = (const float*)smem + hwr * 260;
#pragma unroll
        for (int dd = 0; dd < 32; ++dd) {
            int d = dq + dd * 8;
            outq[(size_t)d * HW_] = qrow[d];
        }
    }
    // ---- encodings 1.0 poke (zeros long since drained by the barriers above)
    if (t < 64) out[8388610 + (size_t)(n0 + t) * 1024 + bestsh[t]] = 1.0f;
    __syncthreads();

    // ---- last block computes loss scalar + perplexity (replaces vq_fin kernel)
    if (t == 0) {
        __threadfence();
        int old = atomicAdd(done, 1);
        lastflag = (old == NBLK_ - 1) ? 1 : 0;
    }
    __syncthreads();
    if (lastflag) {
        double s = 0.0;
#pragma unroll
        for (int j = 0; j < 2; ++j) {
            int k = t * 2 + j;
            int cnt = __hip_atomic_load(&counts[k], __ATOMIC_RELAXED, __HIP_MEMORY_SCOPE_AGENT);
            double p = (double)cnt / 32768.0;
            s += p * log(p + 1e-10);
        }
        for (int o = 32; o > 0; o >>= 1) s += __shfl_down(s, o);
        if (lane == 0) sred2[w] = s;
        __syncthreads();
        if (t == 0) {
            double tot = 0.0;
#pragma unroll
            for (int g = 0; g < 8; ++g) tot += sred2[g];
            double lw = __hip_atomic_load(loss_acc, __ATOMIC_RELAXED, __HIP_MEMORY_SCOPE_AGENT);
            out[0] = (float)(1.25 * lw / (double)QELEMS);
            out[8388609] = (float)exp(-tot);
        }
    }
}

extern "C" void kernel_launch(void* const* d_in, const int* in_sizes, int n_in,
                              void* d_out, int out_size, void* d_ws, size_t ws_size,
                              hipStream_t stream)
{
    const float* x = (const float*)d_in[0];
    const float* emb = (const float*)d_in[1];
    char* ws = (char*)d_ws;
    unsigned short* ebf = (unsigned short*)(ws);                 // 512 KB
    float* enorm = (float*)(ws + 524288);                        // 4 KB
    int* counts = (int*)(ws + 528384);                           // 4 KB
    double* lacc = (double*)(ws + 532480);                       // 8 B
    int* done = (int*)(ws + 532488);                             // 4 B
    float* out = (float*)d_out;

    vq_prep<<<K_, 256, 0, stream>>>(emb, ebf, enorm, counts, lacc, done);
    vq_main<<<NBLK_, 512, 0, stream>>>(x, emb, ebf, enorm, counts, lacc, done, out);
}

// Round 13
// 74.932 us; speedup vs baseline: 1.0240x; 1.0240x over previous
//
#include <hip/hip_runtime.h>
#include <hip/hip_bf16.h>

typedef short short8 __attribute__((ext_vector_type(8)));
typedef float f32x4 __attribute__((ext_vector_type(4)));
typedef unsigned short u16x4 __attribute__((ext_vector_type(4)));

#define D_ 256
#define K_ 1024
#define HW_ 1024
#define NROWS_ 32768
#define QELEMS 8388608  // 32*256*32*32
#define NBLK_ (NROWS_ / 64)

static __device__ __forceinline__ unsigned short to_bf16(float v) {
    __hip_bfloat16 h = __float2bfloat16(v);
    return *(unsigned short*)&h;
}

// ---------------- prep: emb -> bf16 codebook ebf[k][d], enorm[k]=sum e^2, zero counts/loss/done
__global__ __launch_bounds__(256) void vq_prep(const float* __restrict__ emb,
    unsigned short* __restrict__ ebf, float* __restrict__ enorm,
    int* __restrict__ counts, double* __restrict__ loss_acc, int* __restrict__ done)
{
    int k = blockIdx.x, t = threadIdx.x;           // k in [0,1024), t in [0,256)
    float v = emb[k * D_ + t];
    ebf[k * D_ + t] = to_bf16(v);
    float s = v * v;
    for (int o = 32; o > 0; o >>= 1) s += __shfl_down(s, o);
    __shared__ float ws4[4];
    if ((t & 63) == 0) ws4[t >> 6] = s;
    __syncthreads();
    if (t == 0) enorm[k] = ws4[0] + ws4[1] + ws4[2] + ws4[3];
    if (k < 4) counts[k * 256 + t] = 0;
    if (k == 0 && t == 0) { *loss_acc = 0.0; *done = 0; }
}

// ---------------- main: 64 rows/block, 8 waves. Counted-vmcnt ping-pong staging, MFMA argmin,
// enc-zeros riding across barriers, fused scatter/enc/loss, last block computes scalars.
__global__ __launch_bounds__(512, 4) void vq_main(
    const float* __restrict__ x, const float* __restrict__ emb,
    const unsigned short* __restrict__ ebf, const float* __restrict__ enorm,
    int* __restrict__ counts, double* __restrict__ loss_acc, int* __restrict__ done,
    float* __restrict__ out)
{
    // union: [xs 32K | es half0 32K] / later q_lds [64][256] floats (64KB)
    __shared__ char smem[65536];
    __shared__ float xn[64][9];               // per-row |x|^2 partials (per wave)
    __shared__ float ens[1024];               // enorm staged (keeps vmcnt clean in loop)
    __shared__ float rminv[64][4];
    __shared__ int   rmini[64][4];
    __shared__ int   bestsh[64];
    __shared__ double sred2[8];
    __shared__ int lastflag;

    unsigned short* xs = (unsigned short*)smem;   // [0, 32K) during x-stage
    char* es = smem;                              // chunk halves at +0 / +32768

    const int t = threadIdx.x;
    const int n0 = blockIdx.x * 64;
    const int b = n0 >> 10;
    const int hw0 = n0 & 1023;
    const float* xbase = x + (size_t)b * (D_ * HW_) + hw0;

    ens[t] = enorm[t];
    ens[t + 512] = enorm[t + 512];

    // ---- stage x -> bf16 LDS: float4 loads along hw, 4x4 register transpose, b64 writes
    {
        const int rt = t & 15;          // rows 4rt..4rt+3
        const int r0 = rt * 4;
        const int dg = t >> 4;          // 0..31
        float xp[4] = {0.f, 0.f, 0.f, 0.f};
#pragma unroll
        for (int m = 0; m < 2; ++m) {
            int d0 = (dg + 32 * m) * 4;
            f32x4 c[4];
#pragma unroll
            for (int q = 0; q < 4; ++q)
                c[q] = *(const f32x4*)(xbase + (size_t)(d0 + q) * HW_ + r0);
#pragma unroll
            for (int i = 0; i < 4; ++i) {
                u16x4 pk;
                pk[0] = to_bf16(c[0][i]); pk[1] = to_bf16(c[1][i]);
                pk[2] = to_bf16(c[2][i]); pk[3] = to_bf16(c[3][i]);
                xp[i] = fmaf(c[0][i], c[0][i], xp[i]);
                xp[i] = fmaf(c[1][i], c[1][i], xp[i]);
                xp[i] = fmaf(c[2][i], c[2][i], xp[i]);
                xp[i] = fmaf(c[3][i], c[3][i], xp[i]);
                int r = r0 + i;
                int byte = (r * 512 + d0 * 2) ^ ((r & 7) << 4);
                *(u16x4*)((char*)xs + byte) = pk;
            }
        }
        // reduce the 4 dg-groups of this wave: lanes <16 hold row sums for dg=4w..4w+3
#pragma unroll
        for (int i = 0; i < 4; ++i) {
            xp[i] += __shfl_down(xp[i], 32);
            xp[i] += __shfl_down(xp[i], 16);
        }
        if ((t & 48) == 0) {
            int w0 = t >> 6;
#pragma unroll
            for (int i = 0; i < 4; ++i) xn[r0 + i][w0] = xp[i];
        }
    }
    __syncthreads();   // xs + ens resident; drains all vmcnt

    const int lane = t & 63;
    const int w = t >> 6;          // wave 0..7
    const int rh = w & 1;          // row half (32 rows)
    const int cq = w >> 1;         // 16-code tile within 64-chunk
    const int col = lane & 15;
    const int kg = lane >> 4;      // k-group 0..3
    const char* ebf_bytes = (const char*)ebf;
    const int wbyte = w * 4096;

    float2* ezw = (float2*)(out + 8388610 + (size_t)(n0 + w * 8) * 1024);
    const float2 zz2 = {0.f, 0.f};

    // ---- prologue: issue [4 loads chunk0 -> half1][4 enc stores slice15]
    {
#pragma unroll
        for (int j = 0; j < 4; ++j) {
            int p = wbyte + j * 1024 + lane * 16;
            int qq = p ^ (((p >> 9) & 7) << 4);     // inverse-swizzled source
            __builtin_amdgcn_global_load_lds(ebf_bytes + qq, es + 32768 + wbyte + j * 1024, 16, 0, 0);
        }
        __builtin_amdgcn_sched_barrier(0);
        float2* ez = ezw + 15 * 256;
#pragma unroll
        for (int j = 0; j < 4; ++j) ez[j * 64 + lane] = zz2;
        __builtin_amdgcn_sched_barrier(0);
    }

    // ---- A fragments: this wave's 32 rows (2 tiles of 16), ds_read only (lgkm)
    short8 areg[2][8];
#pragma unroll
    for (int rt = 0; rt < 2; ++rt) {
        int row = rh * 32 + rt * 16 + col;
        int rowb = row * 512;
        int sw = (row & 7) << 4;
#pragma unroll
        for (int dc = 0; dc < 8; ++dc) {
            int byte = (rowb + dc * 64 + kg * 16) ^ sw;
            areg[rt][dc] = *(const short8*)((const char*)xs + byte);
        }
    }

    float v1[8]; int i1[8];
#pragma unroll
    for (int s = 0; s < 8; ++s) { v1[s] = 3.4e38f; i1[s] = 0x7fffffff; }

    for (int cc = 0; cc < 16; ++cc) {
        // wait own 4 staging loads (the <=4 left outstanding are the newest ops = enc stores)
        asm volatile("s_waitcnt vmcnt(4)" ::: "memory");
        __builtin_amdgcn_s_barrier();      // all waves' loads for chunk cc complete
        __builtin_amdgcn_sched_barrier(0);
        const int hc = ((cc & 1) ^ 1) * 32768;
        if (cc < 15) {     // issue [4 loads cc+1][4 enc stores slice cc]
            const char* src = ebf_bytes + (size_t)(cc + 1) * 32768;
            const int hn = (cc & 1) * 32768;
#pragma unroll
            for (int j = 0; j < 4; ++j) {
                int p = wbyte + j * 1024 + lane * 16;
                int qq = p ^ (((p >> 9) & 7) << 4);
                __builtin_amdgcn_global_load_lds(src + qq, es + hn + wbyte + j * 1024, 16, 0, 0);
            }
            __builtin_amdgcn_sched_barrier(0);
            float2* ez = ezw + cc * 256;
#pragma unroll
            for (int j = 0; j < 4; ++j) ez[j * 64 + lane] = zz2;
            __builtin_amdgcn_sched_barrier(0);
        }
        const int c0 = cq * 16 + col;
        const int sw0 = (c0 & 7) << 4;
        f32x4 acc0 = {0.f, 0.f, 0.f, 0.f};
        f32x4 acc1 = {0.f, 0.f, 0.f, 0.f};
#pragma unroll
        for (int dc = 0; dc < 8; ++dc) {
            short8 bf = *(const short8*)(es + hc + ((c0 * 512 + dc * 64 + kg * 16) ^ sw0));
            acc0 = __builtin_amdgcn_mfma_f32_16x16x32_bf16(areg[0][dc], bf, acc0, 0, 0, 0);
            acc1 = __builtin_amdgcn_mfma_f32_16x16x32_bf16(areg[1][dc], bf, acc1, 0, 0, 0);
        }
        int code = cc * 64 + c0;
        float bn = ens[code];   // LDS broadcast read (lgkm only, vmcnt untouched)
#pragma unroll
        for (int r = 0; r < 4; ++r) {
            float dv = fmaf(-2.f, acc0[r], bn);
            if (dv < v1[r]) { v1[r] = dv; i1[r] = code; }
            float dw = fmaf(-2.f, acc1[r], bn);
            if (dw < v1[4 + r]) { v1[4 + r] = dw; i1[4 + r] = code; }
        }
    }

    // ---- butterfly min over 16 cols (lane bits 0-3), tie -> lower index
#pragma unroll
    for (int mask = 1; mask < 16; mask <<= 1) {
#pragma unroll
        for (int s = 0; s < 8; ++s) {
            float ov = __shfl_xor(v1[s], mask);
            int oi = __shfl_xor(i1[s], mask);
            if (ov < v1[s] || (ov == v1[s] && oi < i1[s])) { v1[s] = ov; i1[s] = oi; }
        }
    }
    if (col == 0) {
#pragma unroll
        for (int s = 0; s < 8; ++s) {
            int rt = s >> 2, r = s & 3;
            int row = rh * 32 + rt * 16 + kg * 4 + r;
            rminv[row][cq] = v1[s];
            rmini[row][cq] = i1[s];
        }
    }
    __syncthreads();   // drains vmcnt (residual enc stores) + gates es reuse

    // ---- finalize (wave 0): pick across 4 code tiles, counts/loss/bestsh
    if (t < 64) {
        float dmin = rminv[t][0]; int best = rmini[t][0];
#pragma unroll
        for (int g = 1; g < 4; ++g) {
            float cv = rminv[t][g]; int ci = rmini[t][g];
            if (cv < dmin || (cv == dmin && ci < best)) { dmin = cv; best = ci; }
        }
        bestsh[t] = best;
        atomicAdd(&counts[best], 1);
        float s = 0.f;
#pragma unroll
        for (int g = 0; g < 8; ++g) s += xn[t][g];
        float lrow = dmin + s;     // |x-e|^2 = (|e|^2 - 2x.e) + |x|^2
        for (int o = 32; o > 0; o >>= 1) lrow += __shfl_down(lrow, o);
        if (t == 0) atomicAdd(loss_acc, (double)lrow);
    }
    __syncthreads();

    // ---- gather chosen fp32 rows into q_lds[64][256] with XOR(d, r&31) permutation
    {
        int rr = lane >> 3;            // 0..7
        int r  = w * 8 + rr;
        int c  = lane & 7;             // float4 segment
        const f32x4* src4 = (const f32x4*)emb + (size_t)bestsh[r] * 64;
        float* q = (float*)smem + r * 256;
        int xr = r & 31;
#pragma unroll
        for (int j = 0; j < 8; ++j) {
            f32x4 v = src4[8 * j + c];
#pragma unroll
            for (int k = 0; k < 4; ++k) {
                int d = 4 * (8 * j + c) + k;
                q[d ^ xr] = v[k];
            }
        }
    }
    __syncthreads();

    // ---- write quantized out[b][d][hw0+hwr] (wave = 256B contiguous per d)
    {
        const int hwr = t & 63;
        const int dq = t >> 6;
        float* outq = out + 1 + (size_t)b * (D_ * HW_) + hw0 + hwr;
        const float* q = (const float*)smem + hwr * 256;
        int xr = hwr & 31;
#pragma unroll
        for (int dd = 0; dd < 32; ++dd) {
            int d = dq + dd * 8;
            outq[(size_t)d * HW_] = q[d ^ xr];
        }
    }
    // ---- encodings 1.0 poke (zero-stores fully drained by the barriers above)
    if (t < 64) out[8388610 + (size_t)(n0 + t) * 1024 + bestsh[t]] = 1.0f;
    __syncthreads();

    // ---- last block computes loss scalar + perplexity
    if (t == 0) {
        __threadfence();
        int old = atomicAdd(done, 1);
        lastflag = (old == NBLK_ - 1) ? 1 : 0;
    }
    __syncthreads();
    if (lastflag) {
        double s = 0.0;
#pragma unroll
        for (int j = 0; j < 2; ++j) {
            int k = t * 2 + j;
            int cnt = __hip_atomic_load(&counts[k], __ATOMIC_RELAXED, __HIP_MEMORY_SCOPE_AGENT);
            double p = (double)cnt / 32768.0;
            s += p * log(p + 1e-10);
        }
        for (int o = 32; o > 0; o >>= 1) s += __shfl_down(s, o);
        if (lane == 0) sred2[w] = s;
        __syncthreads();
        if (t == 0) {
            double tot = 0.0;
#pragma unroll
            for (int g = 0; g < 8; ++g) tot += sred2[g];
            double lw = __hip_atomic_load(loss_acc, __ATOMIC_RELAXED, __HIP_MEMORY_SCOPE_AGENT);
            out[0] = (float)(1.25 * lw / (double)QELEMS);
            out[8388609] = (float)exp(-tot);
        }
    }
}

extern "C" void kernel_launch(void* const* d_in, const int* in_sizes, int n_in,
                              void* d_out, int out_size, void* d_ws, size_t ws_size,
                              hipStream_t stream)
{
    const float* x = (const float*)d_in[0];
    const float* emb = (const float*)d_in[1];
    char* ws = (char*)d_ws;
    unsigned short* ebf = (unsigned short*)(ws);                 // 512 KB
    float* enorm = (float*)(ws + 524288);                        // 4 KB
    int* counts = (int*)(ws + 528384);                           // 4 KB
    double* lacc = (double*)(ws + 532480);                       // 8 B
    int* done = (int*)(ws + 532488);                             // 4 B
    float* out = (float*)d_out;

    vq_prep<<<K_, 256, 0, stream>>>(emb, ebf, enorm, counts, lacc, done);
    vq_main<<<NBLK_, 512, 0, stream>>>(x, emb, ebf, enorm, counts, lacc, done, out);
}